// Round 4
// baseline (1605.473 us; speedup 1.0000x reference)
//
#include <hip/hip_runtime.h>
#include <stdint.h>

#define DIM_    1024
#define INTER_  512

typedef short bf16x4 __attribute__((ext_vector_type(4)));
typedef short bf16x8 __attribute__((ext_vector_type(8)));
typedef float f32x4  __attribute__((ext_vector_type(4)));

__device__ __forceinline__ unsigned short f2bf(float f) {
  union { float f; unsigned u; } v; v.f = f;
  return (unsigned short)((v.u + 0x7FFFu + ((v.u >> 16) & 1u)) >> 16);
}
__device__ __forceinline__ unsigned f2bf2(float a, float b) {
  union { float f; unsigned u; } va, vb; va.f = a; vb.f = b;
  unsigned ra = (va.u + 0x7FFFu + ((va.u >> 16) & 1u)) >> 16;
  unsigned rb = (vb.u + 0x7FFFu + ((vb.u >> 16) & 1u)) >> 16;
  return ra | (rb << 16);
}
__device__ __forceinline__ float bfhi(unsigned u) {
  union { unsigned u; float f; } v; v.u = u & 0xffff0000u; return v.f;
}
__device__ __forceinline__ float bflo(unsigned u) {
  union { unsigned u; float f; } v; v.u = u << 16; return v.f;
}

__device__ __forceinline__ void gl16(const void* g, void* l) {
  __builtin_amdgcn_global_load_lds(
      (const __attribute__((address_space(1))) unsigned int*)g,
      (__attribute__((address_space(3))) unsigned int*)l, 16, 0, 0);
}

// ---------------------------------------------------------------- gate ----
// One wave per token; fp64 softmax for ref-matching top-k. Also converts the
// token's x row to bf16 (fused cvt_x: row is already being read here).
__global__ __launch_bounds__(256) void gate_kernel(
    const float* __restrict__ x, const float* __restrict__ gw,
    const float* __restrict__ gb, int* __restrict__ idx, float* __restrict__ wts,
    unsigned short* __restrict__ xb) {
  __shared__ double s_sc[4][32];
  __shared__ double s_gs[4][8];
  const int wid = threadIdx.x >> 6, lane = threadIdx.x & 63;
  const int t = blockIdx.x * 4 + wid;
  // fused x -> bf16 (lane covers 16 consecutive floats)
  {
    const float* xrow = x + (size_t)t * DIM_ + lane * 16;
    unsigned short* xbrow = xb + (size_t)t * DIM_ + lane * 16;
    float4 f0 = *(const float4*)(xrow);
    float4 f1 = *(const float4*)(xrow + 4);
    float4 f2v = *(const float4*)(xrow + 8);
    float4 f3v = *(const float4*)(xrow + 12);
    uint4 o0, o1;
    o0.x = f2bf2(f0.x, f0.y);  o0.y = f2bf2(f0.z, f0.w);
    o0.z = f2bf2(f1.x, f1.y);  o0.w = f2bf2(f1.z, f1.w);
    o1.x = f2bf2(f2v.x, f2v.y); o1.y = f2bf2(f2v.z, f2v.w);
    o1.z = f2bf2(f3v.x, f3v.y); o1.w = f2bf2(f3v.z, f3v.w);
    *(uint4*)(xbrow) = o0;
    *(uint4*)(xbrow + 8) = o1;
  }
  const int e = lane & 31, half = lane >> 5;
  const float* xr  = x  + (size_t)t * DIM_ + half * 512;
  const float* gwp = gw + (size_t)half * 512 * 32 + e;
  double a0 = 0, a1 = 0, a2 = 0, a3 = 0;
  for (int k = 0; k < 512; k += 4) {
    float4 xv = *(const float4*)(xr + k);
    a0 += (double)xv.x * (double)gwp[(k + 0) * 32];
    a1 += (double)xv.y * (double)gwp[(k + 1) * 32];
    a2 += (double)xv.z * (double)gwp[(k + 2) * 32];
    a3 += (double)xv.w * (double)gwp[(k + 3) * 32];
  }
  double lg = (a0 + a1) + (a2 + a3);
  lg += __shfl_xor(lg, 32);
  lg += (double)gb[e];
  double m = lg;
  #pragma unroll
  for (int d = 1; d < 32; d <<= 1) m = fmax(m, __shfl_xor(m, d));
  double ex = exp(lg - m);
  double ssum = ex;
  #pragma unroll
  for (int d = 1; d < 32; d <<= 1) ssum += __shfl_xor(ssum, d);
  double sc = ex / ssum;
  double p  = __shfl_xor(sc, 1);
  double m1 = fmax(sc, p), n1 = fmin(sc, p);
  double m2 = __shfl_xor(m1, 2), n2 = __shfl_xor(n1, 2);
  double gs = (m1 >= m2) ? (m1 + fmax(n1, m2)) : (m2 + fmax(n2, m1));
  if (lane < 32) {
    s_sc[wid][e] = sc;
    if ((e & 3) == 0) s_gs[wid][e >> 2] = gs;
  }
  __syncthreads();
  if (lane == 0) {
    unsigned kmask = 0;
    for (int it = 0; it < 4; ++it) {
      int bg = 0; double bv = -1.0;
      for (int g = 0; g < 8; ++g)
        if (!((kmask >> g) & 1u) && s_gs[wid][g] > bv) { bv = s_gs[wid][g]; bg = g; }
      kmask |= 1u << bg;
    }
    unsigned umask = 0;
    for (int slot = 0; slot < 4; ++slot) {
      int be = 0; double bv = -1.0;
      for (int ee = 0; ee < 32; ++ee)
        if (((kmask >> (ee >> 2)) & 1u) && !((umask >> ee) & 1u) && s_sc[wid][ee] > bv) {
          bv = s_sc[wid][ee]; be = ee;
        }
      umask |= 1u << be;
      idx[t * 4 + slot] = be;
      wts[t * 4 + slot] = (float)bv;
    }
  }
}

// ------------------------------------------------- dispatch bookkeeping ----
__global__ __launch_bounds__(256) void count_kernel(const int* __restrict__ idx,
                                                    int* __restrict__ meta) {
  __shared__ int h[32];
  int tid = threadIdx.x;
  if (tid < 32) h[tid] = 0;
  __syncthreads();
  atomicAdd(&h[idx[blockIdx.x * 256 + tid]], 1);
  __syncthreads();
  if (tid < 32 && h[tid]) atomicAdd(&meta[tid], h[tid]);
}

__global__ void scan_kernel(int* __restrict__ meta) {
  int lane = threadIdx.x & 63;
  if (lane < 32) {
    int c = meta[lane];
    int pre = c;
    #pragma unroll
    for (int d = 1; d < 32; d <<= 1) { int t = __shfl_up(pre, d); if (lane >= d) pre += t; }
    int excl = pre - c;
    meta[64 + lane] = excl;
    meta[32 + lane] = excl;
    int nt = (c + 127) >> 7;
    int ntp = nt;
    #pragma unroll
    for (int d = 1; d < 32; d <<= 1) { int t = __shfl_up(ntp, d); if (lane >= d) ntp += t; }
    int ntExcl = ntp - nt;
    for (int k = 0; k < nt; ++k) { meta[128 + ntExcl + k] = lane; meta[1184 + ntExcl + k] = k << 7; }
    if (lane == 31) { meta[96] = excl + c; meta[97] = ntExcl + nt; }
  }
}

__global__ __launch_bounds__(256) void scatter_kernel(
    const int* __restrict__ idx, int* __restrict__ meta,
    int* __restrict__ tok, int* __restrict__ inv) {
  int i = blockIdx.x * 256 + threadIdx.x;
  int lane = threadIdx.x & 63;
  int e = idx[i];
  unsigned long long m = ~0ull;
  #pragma unroll
  for (int b = 0; b < 5; ++b) {
    unsigned long long vote = __ballot((e >> b) & 1);
    m &= ((e >> b) & 1) ? vote : ~vote;
  }
  int leader = __ffsll((long long)m) - 1;
  int rank = __popcll(m & ((1ull << lane) - 1));
  int base = 0;
  if (lane == leader) base = atomicAdd(&meta[32 + e], (int)__popcll(m));
  base = __shfl(base, leader);
  int p = base + rank;
  tok[p] = i >> 2;
  inv[i] = p;
}

// ----------------------------------------------------------- repacking ----
// weight [e][K][N] fp32 -> bf16 LDS-image tiles (4KB): tile=(e,nt,kq).
// Col j's 64B at j*64; 16B slot q holds k-octet (q ^ swz(j)), so a frag read
// (col j, octet g) is ONE ds_read_b128 at j*64 + ((g^swz(j))<<4).
__global__ __launch_bounds__(256) void repack_kernel(
    const float* __restrict__ src, unsigned short* __restrict__ dst,
    int K, int N, int tilesPerMat) {
  const int w = blockIdx.x * 4 + (threadIdx.x >> 6);
  const int j = threadIdx.x & 63;
  const int e = w / tilesPerMat, rem = w % tilesPerMat;
  const int kSteps = K >> 5;
  const int nt = rem / kSteps, kq = rem % kSteps;
  const float* s = src + (size_t)e * K * N + (size_t)(kq * 32) * N + nt * 64 + j;
  float v[32];
  #pragma unroll
  for (int kk = 0; kk < 32; ++kk) v[kk] = s[(size_t)kk * N];
  char* d = (char*)dst + (size_t)w * 4096 + j * 64;
  const int sz = (j & 3) ^ ((j >> 2) & 3);
  #pragma unroll
  for (int q = 0; q < 4; ++q) {
    int o = (q ^ sz) * 8;
    uint4 tv;
    tv.x = f2bf2(v[o + 0], v[o + 1]);
    tv.y = f2bf2(v[o + 2], v[o + 3]);
    tv.z = f2bf2(v[o + 4], v[o + 5]);
    tv.w = f2bf2(v[o + 6], v[o + 7]);
    *(uint4*)(d + q * 16) = tv;
  }
}

// --------------------------------------------------------- shared GEMM1 ----
// BM=128 BN=64 BK=32, dual-B, 2-phase LDS double-buffer.
__global__ __launch_bounds__(256) void s1_kernel(
    const unsigned short* __restrict__ xb, const unsigned short* __restrict__ b1i,
    const unsigned short* __restrict__ b3i, const float* __restrict__ sb1,
    const float* __restrict__ sb3, unsigned short* __restrict__ Hs) {
  __shared__ char lds[32768];
  const int n0 = blockIdx.x * 64;
  const int m0 = blockIdx.y * 128;
  const int tid = threadIdx.x, lane = tid & 63, wave = tid >> 6;
  const int wm = wave >> 1, wn = wave & 1;

  const int r0 = tid >> 2, s0 = tid & 3;
  const int vrw = (r0 & 3) ^ ((r0 >> 2) & 1);
  const char* a0 = (const char*)xb + (size_t)(m0 + r0) * 2048 + ((s0 ^ vrw) << 4);
  const char* a1 = (const char*)xb + (size_t)(m0 + r0 + 64) * 2048 + ((s0 ^ vrw) << 4);
  const char* b1p = (const char*)b1i + (size_t)(blockIdx.x * 32) * 4096 + tid * 16;
  const char* b3p = (const char*)b3i + (size_t)(blockIdx.x * 32) * 4096 + tid * 16;

  const int g = lane >> 4;
  const int vfr = (lane & 3) ^ ((lane >> 2) & 1);
  const int aro = (wm * 64 + (lane & 15)) * 64 + ((g ^ vfr) << 4);
  int bofs[2];
  #pragma unroll
  for (int ni = 0; ni < 2; ++ni) {
    int j = wn * 32 + ni * 16 + (lane & 15);
    int sz = (j & 3) ^ ((j >> 2) & 3);
    bofs[ni] = j * 64 + ((g ^ sz) << 4);
  }

  f32x4 acc1[4][2], acc3[4][2];
  const f32x4 zz = {0.f, 0.f, 0.f, 0.f};
  #pragma unroll
  for (int mi = 0; mi < 4; ++mi)
    #pragma unroll
    for (int ni = 0; ni < 2; ++ni) { acc1[mi][ni] = zz; acc3[mi][ni] = zz; }

  auto stage = [&](int buf, int kq) {
    char* b = lds + buf * 16384;
    gl16(a0 + kq * 64, b + wave * 1024);
    gl16(a1 + kq * 64, b + 4096 + wave * 1024);
    gl16(b1p + (size_t)kq * 4096, b + 8192 + wave * 1024);
    gl16(b3p + (size_t)kq * 4096, b + 12288 + wave * 1024);
  };
  stage(0, 0);
  __syncthreads();
  int cur = 0;
  for (int kq = 0; kq < 32; ++kq) {
    if (kq + 1 < 32) stage(cur ^ 1, kq + 1);
    char* cb = lds + cur * 16384;
    bf16x8 af[4];
    #pragma unroll
    for (int mi = 0; mi < 4; ++mi) af[mi] = *(const bf16x8*)(cb + aro + mi * 1024);
    #pragma unroll
    for (int ni = 0; ni < 2; ++ni) {
      bf16x8 bv = *(const bf16x8*)(cb + 8192 + bofs[ni]);
      #pragma unroll
      for (int mi = 0; mi < 4; ++mi)
        acc1[mi][ni] = __builtin_amdgcn_mfma_f32_16x16x32_bf16(af[mi], bv, acc1[mi][ni], 0, 0, 0);
      bf16x8 bv3 = *(const bf16x8*)(cb + 12288 + bofs[ni]);
      #pragma unroll
      for (int mi = 0; mi < 4; ++mi)
        acc3[mi][ni] = __builtin_amdgcn_mfma_f32_16x16x32_bf16(af[mi], bv3, acc3[mi][ni], 0, 0, 0);
    }
    __syncthreads();
    cur ^= 1;
  }
  #pragma unroll
  for (int ni = 0; ni < 2; ++ni) {
    int col = n0 + wn * 32 + ni * 16 + (lane & 15);
    float bb1 = sb1[col], bb3 = sb3[col];
    #pragma unroll
    for (int mi = 0; mi < 4; ++mi) {
      int rb = wm * 64 + mi * 16 + ((lane >> 4) << 2);
      #pragma unroll
      for (int r = 0; r < 4; ++r) {
        int row = m0 + rb + r;
        float v1 = acc1[mi][ni][r] + bb1;
        float v3 = acc3[mi][ni][r] + bb3;
        float h = (v1 / (1.f + __expf(-v1))) * v3;
        Hs[(size_t)row * 1024 + col] = f2bf(h);
      }
    }
  }
}

// --------------------------------------------------------- shared GEMM2 ----
__global__ __launch_bounds__(256) void s2_kernel(
    const unsigned short* __restrict__ Hs, const unsigned short* __restrict__ b2i,
    const float* __restrict__ sb2, float* __restrict__ out) {
  __shared__ char lds[32768];
  const int n0 = blockIdx.x * 128;
  const int m0 = blockIdx.y * 128;
  const int tid = threadIdx.x, lane = tid & 63, wave = tid >> 6;
  const int wm = wave >> 1, wn = wave & 1;

  const int r0 = tid >> 2, s0 = tid & 3;
  const int vrw = (r0 & 3) ^ ((r0 >> 2) & 1);
  const char* a0 = (const char*)Hs + (size_t)(m0 + r0) * 2048 + ((s0 ^ vrw) << 4);
  const char* a1 = (const char*)Hs + (size_t)(m0 + r0 + 64) * 2048 + ((s0 ^ vrw) << 4);
  const char* bp0 = (const char*)b2i + (size_t)((blockIdx.x * 2 + 0) * 32) * 4096 + tid * 16;
  const char* bp1 = (const char*)b2i + (size_t)((blockIdx.x * 2 + 1) * 32) * 4096 + tid * 16;

  const int g = lane >> 4;
  const int vfr = (lane & 3) ^ ((lane >> 2) & 1);
  const int aro = (wm * 64 + (lane & 15)) * 64 + ((g ^ vfr) << 4);
  int bofs[4];
  #pragma unroll
  for (int ni = 0; ni < 4; ++ni) {
    int j = wn * 64 + ni * 16 + (lane & 15);
    int sz = (j & 3) ^ ((j >> 2) & 3);
    bofs[ni] = 8192 + (j >> 6) * 4096 + (j & 63) * 64 + ((g ^ sz) << 4);
  }
  f32x4 acc[4][4];
  const f32x4 zz = {0.f, 0.f, 0.f, 0.f};
  #pragma unroll
  for (int mi = 0; mi < 4; ++mi)
    #pragma unroll
    for (int ni = 0; ni < 4; ++ni) acc[mi][ni] = zz;

  auto stage = [&](int buf, int kq) {
    char* b = lds + buf * 16384;
    gl16(a0 + kq * 64, b + wave * 1024);
    gl16(a1 + kq * 64, b + 4096 + wave * 1024);
    gl16(bp0 + (size_t)kq * 4096, b + 8192 + wave * 1024);
    gl16(bp1 + (size_t)kq * 4096, b + 12288 + wave * 1024);
  };
  stage(0, 0);
  __syncthreads();
  int cur = 0;
  for (int kq = 0; kq < 32; ++kq) {
    if (kq + 1 < 32) stage(cur ^ 1, kq + 1);
    char* cb = lds + cur * 16384;
    bf16x8 af[4];
    #pragma unroll
    for (int mi = 0; mi < 4; ++mi) af[mi] = *(const bf16x8*)(cb + aro + mi * 1024);
    #pragma unroll
    for (int ni = 0; ni < 4; ++ni) {
      bf16x8 bv = *(const bf16x8*)(cb + bofs[ni]);
      #pragma unroll
      for (int mi = 0; mi < 4; ++mi)
        acc[mi][ni] = __builtin_amdgcn_mfma_f32_16x16x32_bf16(af[mi], bv, acc[mi][ni], 0, 0, 0);
    }
    __syncthreads();
    cur ^= 1;
  }
  #pragma unroll
  for (int ni = 0; ni < 4; ++ni) {
    int col = n0 + wn * 64 + ni * 16 + (lane & 15);
    float bb = sb2[col];
    #pragma unroll
    for (int mi = 0; mi < 4; ++mi) {
      int rb = m0 + wm * 64 + mi * 16 + ((lane >> 4) << 2);
      #pragma unroll
      for (int r = 0; r < 4; ++r)
        out[(size_t)(rb + r) * 1024 + col] = acc[mi][ni][r] + bb;
    }
  }
}

// --------------------------------------------------------- routed GEMM1 ----
__global__ __launch_bounds__(256) void g1_kernel(
    const unsigned short* __restrict__ xb, const unsigned short* __restrict__ w1i,
    const unsigned short* __restrict__ w3i, const float* __restrict__ b1,
    const float* __restrict__ b3, const int* __restrict__ tok,
    const int* __restrict__ meta, unsigned short* __restrict__ H) {
  __shared__ char lds[32768];
  if ((int)blockIdx.y >= meta[97]) return;
  const int e = meta[128 + blockIdx.y], m0 = meta[1184 + blockIdx.y];
  const int off_e = meta[64 + e], nrem = meta[e] - m0;
  const int n0 = blockIdx.x * 64;
  const int tid = threadIdx.x, lane = tid & 63, wave = tid >> 6;
  const int wm = wave >> 1, wn = wave & 1;

  const int r0 = tid >> 2, s0 = tid & 3;
  const int vrw = (r0 & 3) ^ ((r0 >> 2) & 1);
  int tr0 = tok[off_e + m0 + ((r0 < nrem) ? r0 : 0)];
  int tr1 = tok[off_e + m0 + ((r0 + 64 < nrem) ? r0 + 64 : 0)];
  const char* a0 = (const char*)xb + (size_t)tr0 * 2048 + ((s0 ^ vrw) << 4);
  const char* a1 = (const char*)xb + (size_t)tr1 * 2048 + ((s0 ^ vrw) << 4);
  const char* b1p = (const char*)w1i + (size_t)((e * 8 + blockIdx.x) * 32) * 4096 + tid * 16;
  const char* b3p = (const char*)w3i + (size_t)((e * 8 + blockIdx.x) * 32) * 4096 + tid * 16;

  const int g = lane >> 4;
  const int vfr = (lane & 3) ^ ((lane >> 2) & 1);
  const int aro = (wm * 64 + (lane & 15)) * 64 + ((g ^ vfr) << 4);
  int bofs[2];
  #pragma unroll
  for (int ni = 0; ni < 2; ++ni) {
    int j = wn * 32 + ni * 16 + (lane & 15);
    int sz = (j & 3) ^ ((j >> 2) & 3);
    bofs[ni] = j * 64 + ((g ^ sz) << 4);
  }

  f32x4 acc1[4][2], acc3[4][2];
  const f32x4 zz = {0.f, 0.f, 0.f, 0.f};
  #pragma unroll
  for (int mi = 0; mi < 4; ++mi)
    #pragma unroll
    for (int ni = 0; ni < 2; ++ni) { acc1[mi][ni] = zz; acc3[mi][ni] = zz; }

  auto stage = [&](int buf, int kq) {
    char* b = lds + buf * 16384;
    gl16(a0 + kq * 64, b + wave * 1024);
    gl16(a1 + kq * 64, b + 4096 + wave * 1024);
    gl16(b1p + (size_t)kq * 4096, b + 8192 + wave * 1024);
    gl16(b3p + (size_t)kq * 4096, b + 12288 + wave * 1024);
  };
  stage(0, 0);
  __syncthreads();
  int cur = 0;
  for (int kq = 0; kq < 32; ++kq) {
    if (kq + 1 < 32) stage(cur ^ 1, kq + 1);
    char* cb = lds + cur * 16384;
    bf16x8 af[4];
    #pragma unroll
    for (int mi = 0; mi < 4; ++mi) af[mi] = *(const bf16x8*)(cb + aro + mi * 1024);
    #pragma unroll
    for (int ni = 0; ni < 2; ++ni) {
      bf16x8 bv = *(const bf16x8*)(cb + 8192 + bofs[ni]);
      #pragma unroll
      for (int mi = 0; mi < 4; ++mi)
        acc1[mi][ni] = __builtin_amdgcn_mfma_f32_16x16x32_bf16(af[mi], bv, acc1[mi][ni], 0, 0, 0);
      bf16x8 bv3 = *(const bf16x8*)(cb + 12288 + bofs[ni]);
      #pragma unroll
      for (int mi = 0; mi < 4; ++mi)
        acc3[mi][ni] = __builtin_amdgcn_mfma_f32_16x16x32_bf16(af[mi], bv3, acc3[mi][ni], 0, 0, 0);
    }
    __syncthreads();
    cur ^= 1;
  }
  #pragma unroll
  for (int ni = 0; ni < 2; ++ni) {
    int col = n0 + wn * 32 + ni * 16 + (lane & 15);
    float bb1 = b1[e * 512 + col], bb3 = b3[e * 512 + col];
    #pragma unroll
    for (int mi = 0; mi < 4; ++mi) {
      int rb = wm * 64 + mi * 16 + ((lane >> 4) << 2);
      #pragma unroll
      for (int r = 0; r < 4; ++r) {
        int row = rb + r;
        if (row < nrem) {
          float v1 = acc1[mi][ni][r] + bb1;
          float v3 = acc3[mi][ni][r] + bb3;
          float h = (v1 / (1.f + __expf(-v1))) * v3;
          H[(size_t)(off_e + m0 + row) * 512 + col] = f2bf(h);
        }
      }
    }
  }
}

// --------------------------------------------------------- routed GEMM2 ----
// Y[pos][512] = (H@w2e + b2e) for one column half (cbase). NO atomics.
__global__ __launch_bounds__(256) void g2_kernel(
    const unsigned short* __restrict__ H, const unsigned short* __restrict__ w2i,
    const float* __restrict__ b2, const int* __restrict__ meta,
    unsigned short* __restrict__ Y, int cbase) {
  __shared__ char lds[32768];
  if ((int)blockIdx.y >= meta[97]) return;
  const int e = meta[128 + blockIdx.y], m0 = meta[1184 + blockIdx.y];
  const int off_e = meta[64 + e], nrem = meta[e] - m0;
  const int n0 = cbase + blockIdx.x * 128;
  const int tid = threadIdx.x, lane = tid & 63, wave = tid >> 6;
  const int wm = wave >> 1, wn = wave & 1;

  const int r0 = tid >> 2, s0 = tid & 3;
  const int vrw = (r0 & 3) ^ ((r0 >> 2) & 1);
  const char* a0 = (const char*)H + (size_t)(off_e + m0 + ((r0 < nrem) ? r0 : 0)) * 1024 + ((s0 ^ vrw) << 4);
  const char* a1 = (const char*)H + (size_t)(off_e + m0 + ((r0 + 64 < nrem) ? r0 + 64 : 0)) * 1024 + ((s0 ^ vrw) << 4);
  const int ntb = n0 >> 6;
  const char* bp0 = (const char*)w2i + (size_t)((e * 16 + ntb + 0) * 16) * 4096 + tid * 16;
  const char* bp1 = (const char*)w2i + (size_t)((e * 16 + ntb + 1) * 16) * 4096 + tid * 16;

  const int g = lane >> 4;
  const int vfr = (lane & 3) ^ ((lane >> 2) & 1);
  const int aro = (wm * 64 + (lane & 15)) * 64 + ((g ^ vfr) << 4);
  int bofs[4];
  #pragma unroll
  for (int ni = 0; ni < 4; ++ni) {
    int j = wn * 64 + ni * 16 + (lane & 15);
    int sz = (j & 3) ^ ((j >> 2) & 3);
    bofs[ni] = 8192 + (j >> 6) * 4096 + (j & 63) * 64 + ((g ^ sz) << 4);
  }
  f32x4 acc[4][4];
  const f32x4 zz = {0.f, 0.f, 0.f, 0.f};
  #pragma unroll
  for (int mi = 0; mi < 4; ++mi)
    #pragma unroll
    for (int ni = 0; ni < 4; ++ni) acc[mi][ni] = zz;

  auto stage = [&](int buf, int kq) {
    char* b = lds + buf * 16384;
    gl16(a0 + kq * 64, b + wave * 1024);
    gl16(a1 + kq * 64, b + 4096 + wave * 1024);
    gl16(bp0 + (size_t)kq * 4096, b + 8192 + wave * 1024);
    gl16(bp1 + (size_t)kq * 4096, b + 12288 + wave * 1024);
  };
  stage(0, 0);
  __syncthreads();
  int cur = 0;
  for (int kq = 0; kq < 16; ++kq) {
    if (kq + 1 < 16) stage(cur ^ 1, kq + 1);
    char* cb = lds + cur * 16384;
    bf16x8 af[4];
    #pragma unroll
    for (int mi = 0; mi < 4; ++mi) af[mi] = *(const bf16x8*)(cb + aro + mi * 1024);
    #pragma unroll
    for (int ni = 0; ni < 4; ++ni) {
      bf16x8 bv = *(const bf16x8*)(cb + bofs[ni]);
      #pragma unroll
      for (int mi = 0; mi < 4; ++mi)
        acc[mi][ni] = __builtin_amdgcn_mfma_f32_16x16x32_bf16(af[mi], bv, acc[mi][ni], 0, 0, 0);
    }
    __syncthreads();
    cur ^= 1;
  }
  #pragma unroll
  for (int ni = 0; ni < 4; ++ni) {
    int col = n0 + wn * 64 + ni * 16 + (lane & 15);
    float bb = b2[e * 1024 + col];
    int ycol = col - cbase;
    #pragma unroll
    for (int mi = 0; mi < 4; ++mi) {
      int rb = wm * 64 + mi * 16 + ((lane >> 4) << 2);
      #pragma unroll
      for (int r = 0; r < 4; ++r) {
        int row = rb + r;
        if (row < nrem)
          Y[(size_t)(off_e + m0 + row) * 512 + ycol] = f2bf(acc[mi][ni][r] + bb);
      }
    }
  }
}

// ------------------------------------------------------------- combine ----
__global__ __launch_bounds__(256) void combine_kernel(
    const unsigned short* __restrict__ Y, const int* __restrict__ inv,
    const float* __restrict__ wts, float* __restrict__ out, int cbase) {
  int t = blockIdx.x * 2 + (threadIdx.x >> 7);
  int c = (threadIdx.x & 127) * 4;
  int4 iv = *(const int4*)(inv + t * 4);
  float4 wv = *(const float4*)(wts + t * 4);
  float* op = out + (size_t)t * 1024 + cbase + c;
  float4 o = *(float4*)op;
  uint2 u;
  u = *(const uint2*)(Y + (size_t)iv.x * 512 + c);
  o.x += wv.x * bflo(u.x); o.y += wv.x * bfhi(u.x);
  o.z += wv.x * bflo(u.y); o.w += wv.x * bfhi(u.y);
  u = *(const uint2*)(Y + (size_t)iv.y * 512 + c);
  o.x += wv.y * bflo(u.x); o.y += wv.y * bfhi(u.x);
  o.z += wv.y * bflo(u.y); o.w += wv.y * bfhi(u.y);
  u = *(const uint2*)(Y + (size_t)iv.z * 512 + c);
  o.x += wv.z * bflo(u.x); o.y += wv.z * bfhi(u.x);
  o.z += wv.z * bflo(u.y); o.w += wv.z * bfhi(u.y);
  u = *(const uint2*)(Y + (size_t)iv.w * 512 + c);
  o.x += wv.w * bflo(u.x); o.y += wv.w * bfhi(u.x);
  o.z += wv.w * bflo(u.y); o.w += wv.w * bfhi(u.y);
  *(float4*)op = o;
}

// ------------------------------------------------------------------ host ----
extern "C" void kernel_launch(void* const* d_in, const int* in_sizes, int n_in,
                              void* d_out, int out_size, void* d_ws, size_t ws_size,
                              hipStream_t stream) {
  const float* x   = (const float*)d_in[0];
  const float* gw  = (const float*)d_in[1];
  const float* gb  = (const float*)d_in[2];
  const float* w1  = (const float*)d_in[3];
  const float* b1  = (const float*)d_in[4];
  const float* w3  = (const float*)d_in[5];
  const float* b3  = (const float*)d_in[6];
  const float* w2  = (const float*)d_in[7];
  const float* b2  = (const float*)d_in[8];
  const float* sw1 = (const float*)d_in[9];
  const float* sb1 = (const float*)d_in[10];
  const float* sw3 = (const float*)d_in[11];
  const float* sb3 = (const float*)d_in[12];
  const float* sw2 = (const float*)d_in[13];
  const float* sb2 = (const float*)d_in[14];
  float* out = (float*)d_out;
  char* ws = (char*)d_ws;

  const size_t OFF_XB   = 134217728;
  const size_t OFF_W1I  = 201326592;
  const size_t OFF_W3I  = 234881024;
  const size_t OFF_W2I  = 268435456;
  const size_t OFF_SW1I = 301989888;
  const size_t OFF_SW3I = 304087040;
  const size_t OFF_SW2I = 306184192;
  const size_t OFF_IDX  = 308281344;
  const size_t OFF_WTS  = 308805632;
  const size_t OFF_TOK  = 309329920;
  const size_t OFF_INV  = 309854208;
  const size_t OFF_META = 310378496;
  if (ws_size < OFF_META + 8960) return;

  unsigned short* H    = (unsigned short*)ws;
  unsigned short* xb   = (unsigned short*)(ws + OFF_XB);
  unsigned short* Yb   = (unsigned short*)(ws + OFF_XB);   // aliases xb/w1i/w3i
  unsigned short* w1i  = (unsigned short*)(ws + OFF_W1I);
  unsigned short* w3i  = (unsigned short*)(ws + OFF_W3I);
  unsigned short* w2i  = (unsigned short*)(ws + OFF_W2I);
  unsigned short* sw1i = (unsigned short*)(ws + OFF_SW1I);
  unsigned short* sw3i = (unsigned short*)(ws + OFF_SW3I);
  unsigned short* sw2i = (unsigned short*)(ws + OFF_SW2I);
  int*   idx  = (int*)(ws + OFF_IDX);
  float* wts  = (float*)(ws + OFF_WTS);
  int*   tokl = (int*)(ws + OFF_TOK);
  int*   inv  = (int*)(ws + OFF_INV);
  int*   meta = (int*)(ws + OFF_META);

  hipMemsetAsync(meta, 0, 128, stream);
  gate_kernel<<<dim3(8192), dim3(256), 0, stream>>>(x, gw, gb, idx, wts, xb);
  count_kernel<<<dim3(512), dim3(256), 0, stream>>>(idx, meta);
  scan_kernel<<<dim3(1), dim3(64), 0, stream>>>(meta);
  scatter_kernel<<<dim3(512), dim3(256), 0, stream>>>(idx, meta, tokl, inv);
  repack_kernel<<<dim3(2048), dim3(256), 0, stream>>>(w1, w1i, 1024, 512, 256);
  repack_kernel<<<dim3(2048), dim3(256), 0, stream>>>(w3, w3i, 1024, 512, 256);
  repack_kernel<<<dim3(2048), dim3(256), 0, stream>>>(w2, w2i, 512, 1024, 256);
  repack_kernel<<<dim3(128), dim3(256), 0, stream>>>(sw1, sw1i, 1024, 1024, 512);
  repack_kernel<<<dim3(128), dim3(256), 0, stream>>>(sw3, sw3i, 1024, 1024, 512);
  repack_kernel<<<dim3(128), dim3(256), 0, stream>>>(sw2, sw2i, 1024, 1024, 512);
  s1_kernel<<<dim3(16, 256), dim3(256), 0, stream>>>(xb, sw1i, sw3i, sb1, sb3, H);
  s2_kernel<<<dim3(8, 256), dim3(256), 0, stream>>>(H, sw2i, sb2, out);
  g1_kernel<<<dim3(8, 1056), dim3(256), 0, stream>>>(xb, w1i, w3i, b1, b3, tokl, meta, H);
  g2_kernel<<<dim3(4, 1056), dim3(256), 0, stream>>>(H, w2i, b2, meta, Yb, 0);
  combine_kernel<<<dim3(16384), dim3(256), 0, stream>>>(Yb, inv, wts, out, 0);
  g2_kernel<<<dim3(4, 1056), dim3(256), 0, stream>>>(H, w2i, b2, meta, Yb, 512);
  combine_kernel<<<dim3(16384), dim3(256), 0, stream>>>(Yb, inv, wts, out, 512);
}